// Round 6
// baseline (506.432 us; speedup 1.0000x reference)
//
#include <hip/hip_runtime.h>
#include <hip/hip_bf16.h>

#define N_NODES 100000
#define E_EDGES 1600000
#define NG 512
#define FIN 7
#define HID 128
#define NBUCK 782          // ceil(N_NODES/128), bucket = 128 consecutive dst nodes
#define NBLK_SC 256        // partition blocks (each owns a contiguous edge chunk)
#define CHUNK 6250         // E_EDGES / NBLK_SC (exact)
#define TLEN (NBUCK * NBLK_SC)   // 200192 table entries
#define NCH 196            // ceil(TLEN/1024) scan chunks
#define MMX_GRID 782       // ceil(N_NODES/128)
#define AGGW_GRID 25000    // N_NODES waves, 4 waves per block
#define L1_GRID 25000      // N_NODES / 4 nodes per block (1 node per wave)
#define PROJ_GRID 25000    // N_NODES waves, 4 waves per block
#define AGG2_GRID 6250     // N_NODES / 16 nodes per block (16 lanes per node)

typedef __attribute__((ext_vector_type(8))) short bf16x8;
typedef __attribute__((ext_vector_type(4))) float f32x4;

// bf16 helpers: decode packed pair, encode with RNE
__device__ __forceinline__ float bf_lo(unsigned int u) { return __uint_as_float(u << 16); }
__device__ __forceinline__ float bf_hi(unsigned int u) { return __uint_as_float(u & 0xffff0000u); }
__device__ __forceinline__ unsigned int f2bf_rne(float f) {
    unsigned int x = __float_as_uint(f);
    return (x + 0x7fffu + ((x >> 16) & 1u)) >> 16;   // finite inputs only
}
__device__ __forceinline__ unsigned int pack_bf2(float lo, float hi) {
    return f2bf_rne(lo) | (f2bf_rne(hi) << 16);
}

// ------ CSR hist (0..255) + [Wc fold + bc + pooled2 zero] (256) + WT2/WT3 (257..384)

__global__ __launch_bounds__(256) void k_hist2(const int* __restrict__ eidx,
                                               int* __restrict__ table,
                                               const float* __restrict__ W4,
                                               const float* __restrict__ b4,
                                               const float* __restrict__ Wlin,
                                               const float* __restrict__ blin,
                                               float* __restrict__ Wc,
                                               float* __restrict__ bc,
                                               float* __restrict__ pooled2,
                                               const float* __restrict__ W2,
                                               const float* __restrict__ W3,
                                               unsigned short* __restrict__ WT2,
                                               unsigned short* __restrict__ WT3) {
    __shared__ int h[NBUCK];
    int blk = blockIdx.x, t = threadIdx.x;
    if (blk >= NBLK_SC) {
        int r = blk - NBLK_SC;
        if (r == 0) {
            // zero pooled2 (512*2 floats = 1024)
            float4 z = {0.f, 0.f, 0.f, 0.f};
            *(float4*)&pooled2[t * 4] = z;
            int k = t >> 1, o = t & 1;
            float acc = 0.f;
            for (int j = 0; j < HID; ++j) acc += W4[k * HID + j] * Wlin[j * 2 + o];
            Wc[k * 2 + o] = acc;
            if (k == 0) {
                float b = blin[o];
                for (int j = 0; j < HID; ++j) b += b4[j] * Wlin[j * 2 + o];
                bc[o] = b;
            }
        } else if (r < 65) {    // WT2: transpose+convert, 64 blocks x 256 = 16384 elems
            int idx = (r - 1) * 256 + t;
            int k = idx >> 7, n = idx & 127;
            WT2[n * 128 + k] = (unsigned short)f2bf_rne(W2[idx]);
        } else {                // WT3
            int idx = (r - 65) * 256 + t;
            int k = idx >> 7, n = idx & 127;
            WT3[n * 128 + k] = (unsigned short)f2bf_rne(W3[idx]);
        }
        return;
    }
    for (int i = t; i < NBUCK; i += 256) h[i] = 0;
    __syncthreads();
    int e0 = blk * CHUNK, e1 = e0 + CHUNK;
    for (int e = e0 + t; e < e1; e += 256)
        atomicAdd(&h[eidx[E_EDGES + e] >> 7], 1);
    __syncthreads();
    for (int i = t; i < NBUCK; i += 256)
        table[i * NBLK_SC + blk] = h[i];
}

__global__ void k_blocksum(const int* __restrict__ table, int* __restrict__ partial) {
    __shared__ int s[256];
    int b = blockIdx.x, t = threadIdx.x;
    int base = b * 1024;
    int sum = 0;
    for (int i = t; i < 1024; i += 256) {
        int idx = base + i;
        sum += (idx < TLEN) ? table[idx] : 0;
    }
    s[t] = sum; __syncthreads();
    for (int st = 128; st > 0; st >>= 1) {
        if (t < st) s[t] += s[t + st];
        __syncthreads();
    }
    if (t == 0) partial[b] = s[0];
}

// parallel exclusive scan of the 196 chunk sums (one 256-thread block)
__global__ void k_scan_blk(int* __restrict__ partial, int* __restrict__ bucketBase,
                           int* __restrict__ rowptr) {
    __shared__ int s[256];
    int t = threadIdx.x;
    int v = (t < NCH) ? partial[t] : 0;
    s[t] = v; __syncthreads();
    for (int st = 1; st < 256; st <<= 1) {
        int a = (t >= st) ? s[t - st] : 0;
        __syncthreads();
        s[t] += a;
        __syncthreads();
    }
    if (t < NCH) partial[t] = s[t] - v;   // exclusive
    if (t == 0) { bucketBase[NBUCK] = E_EDGES; rowptr[N_NODES] = E_EDGES; }
}

__global__ void k_scan_final(int* __restrict__ table, const int* __restrict__ partial,
                             int* __restrict__ bucketBase) {
    __shared__ int s[1024];
    int b = blockIdx.x, t = threadIdx.x;
    int idx = b * 1024 + t;
    int v = (idx < TLEN) ? table[idx] : 0;
    s[t] = v; __syncthreads();
    for (int st = 1; st < 1024; st <<= 1) {
        int add = (t >= st) ? s[t - st] : 0;
        __syncthreads();
        s[t] += add;
        __syncthreads();
    }
    if (idx < TLEN) {
        int ex = partial[b] + s[t] - v;   // exclusive
        table[idx] = ex;
        if ((idx & (NBLK_SC - 1)) == 0) bucketBase[idx / NBLK_SC] = ex;
    }
}

__global__ __launch_bounds__(256) void k_scatter2(const int* __restrict__ eidx,
                                                  const int* __restrict__ table,
                                                  unsigned int* __restrict__ ebuf) {
    __shared__ int loff[NBUCK];
    int blk = blockIdx.x, t = threadIdx.x;
    for (int i = t; i < NBUCK; i += 256) loff[i] = table[i * NBLK_SC + blk];
    __syncthreads();
    int e0 = blk * CHUNK, e1 = e0 + CHUNK;
    for (int e = e0 + t; e < e1; e += 256) {
        int s = eidx[e];
        int d = eidx[E_EDGES + e];
        int p = atomicAdd(&loff[d >> 7], 1);
        ebuf[p] = ((unsigned int)(d & 127) << 17) | (unsigned int)s;
    }
}

// col[] stores plain src node id. Also emits xs[n][0..7] = dinv[n]*x[n] (pad 0) for k_l1.
__global__ __launch_bounds__(256) void k_bucket(const unsigned int* __restrict__ ebuf,
                                                const int* __restrict__ bucketBase,
                                                int* __restrict__ rowptr,
                                                float* __restrict__ dinv,
                                                int* __restrict__ col,
                                                const float* __restrict__ x,
                                                float* __restrict__ xs) {
    __shared__ int scnt[128], soff[128], scur[128];
    int b = blockIdx.x, t = threadIdx.x;
    int bbase = bucketBase[b], bend = bucketBase[b + 1];
    if (t < 128) { scnt[t] = 0; scur[t] = 0; }
    __syncthreads();
    for (int e = bbase + t; e < bend; e += 256) {
        unsigned int rec = ebuf[e];
        atomicAdd(&scnt[rec >> 17], 1);
    }
    __syncthreads();
    if (t < 128) soff[t] = scnt[t];
    __syncthreads();
    for (int st = 1; st < 128; st <<= 1) {
        int a = (t < 128 && t >= st) ? soff[t - st] : 0;
        __syncthreads();
        if (t < 128) soff[t] += a;
        __syncthreads();
    }
    float dval = 0.f;
    if (t < 128) {
        int ex = soff[t] - scnt[t];
        int node = b * 128 + t;
        if (node < N_NODES) {
            rowptr[node] = bbase + ex;
            dval = rsqrtf((float)(scnt[t] + 1));   // +1 self-loop
            dinv[node] = dval;
        }
        soff[t] = ex;
    }
    __syncthreads();
    for (int e = bbase + t; e < bend; e += 256) {
        unsigned int rec = ebuf[e];
        int dl = rec >> 17;
        int s = rec & 0x1FFFF;
        int p = bbase + soff[dl] + atomicAdd(&scur[dl], 1);
        col[p] = s;
    }
    // pre-scaled padded input rows for k_l1 (threads >=128 have exited the loop)
    if (t < 128) {
        int node = b * 128 + t;
        if (node < N_NODES) {
            float4 v0, v1;
            v0.x = dval * x[node * 7 + 0];
            v0.y = dval * x[node * 7 + 1];
            v0.z = dval * x[node * 7 + 2];
            v0.w = dval * x[node * 7 + 3];
            v1.x = dval * x[node * 7 + 4];
            v1.y = dval * x[node * 7 + 5];
            v1.z = dval * x[node * 7 + 6];
            v1.w = 0.f;
            *(float4*)&xs[node * 8] = v0;
            *(float4*)&xs[node * 8 + 4] = v1;
        }
    }
}

// ---------------- fused layer 1: g1 = bf16(dinv * relu((A' x) W1 + b1)) ----------------
// One wave per node. Gather phase: 8 lanes per edge (lane = g*8+r), 8 edges per step,
// acc[r] += xs[s][r]. Self term in GROUP 0 ONLY (butterfly sums across groups).

__global__ __launch_bounds__(256) void k_l1(const float* __restrict__ xs,
                                            const float* __restrict__ W1,
                                            const float* __restrict__ b1,
                                            const int* __restrict__ rowptr,
                                            const int* __restrict__ col,
                                            const float* __restrict__ dinv,
                                            unsigned int* __restrict__ g1) {
    __shared__ float w1s[FIN * HID];   // 3.5 KB
    __shared__ float b1s[HID];
    int t = threadIdx.x;
    for (int i = t; i < FIN * HID; i += 256) w1s[i] = W1[i];
    if (t < HID) b1s[t] = b1[t];
    __syncthreads();

    int lane = t & 63, wave = t >> 6;
    int g = lane >> 3, r = lane & 7;
    int node = blockIdx.x * 4 + wave;            // grid exact: 25000*4 = N_NODES
    float di = dinv[node];
    float acc = (g == 0) ? xs[node * 8 + r] : 0.f;   // self term once (group 0 only)
    int e0 = rowptr[node], e1 = rowptr[node + 1];

    for (int base = e0; base < e1; base += 64) {
        int m = e1 - base; if (m > 64) m = 64;
        int cv = col[base + lane];               // over-read past e1 safe (ebuf region)
        int j = 0;
        for (; j + 8 <= m; j += 8) {
            int s = __shfl(cv, j + g);
            acc += xs[s * 8 + r];
        }
        if (j < m) {
            int jg = j + g;
            int idx = (jg < m) ? jg : j;         // j < m here, so idx always valid
            int s = __shfl(cv, idx);
            float u = xs[s * 8 + r];
            if (jg < m) acc += u;
        }
    }
    // reduce across the 8 edge-groups: every lane gets the full sum for feature r
    acc += __shfl_xor(acc, 8);
    acc += __shfl_xor(acc, 16);
    acc += __shfl_xor(acc, 32);
    acc *= di;                                   // outer dinv_i of the symmetric norm

    // broadcast the 7 aggregated features, project: lane -> outputs 2l, 2l+1
    float av[FIN];
    #pragma unroll
    for (int k = 0; k < FIN; ++k) av[k] = __shfl(acc, k);
    float2 bb = *(const float2*)&b1s[2 * lane];
    float acc0 = bb.x, acc1 = bb.y;
    #pragma unroll
    for (int k = 0; k < FIN; ++k) {
        float2 w = *(const float2*)&w1s[k * HID + 2 * lane];
        acc0 += av[k] * w.x;
        acc1 += av[k] * w.y;
    }
    g1[(size_t)node * 64 + lane] = pack_bf2(di * fmaxf(acc0, 0.f), di * fmaxf(acc1, 0.f));
}

// ---------------- aggregation: wave/node, pre-scaled rows, prefetched windows --------
// At the compulsory-fetch floor (8 XCDs x 25.6 MB buffer ~= 192 MB measured): leave as is.

__global__ __launch_bounds__(256) void k_aggW(const unsigned int* __restrict__ gIn,
                                              unsigned int* __restrict__ gOut,
                                              const int* __restrict__ rowptr,
                                              const int* __restrict__ colv,
                                              const float* __restrict__ dinv) {
    int wid = (blockIdx.x * blockDim.x + threadIdx.x) >> 6;
    int lane = threadIdx.x & 63;
    if (wid >= N_NODES) return;
    int i = wid;
    float di = dinv[i];
    int e0 = rowptr[i], e1 = rowptr[i + 1];
    int cv = colv[e0 + lane];                     // over-read past e1 is safe/unused
    unsigned int v = gIn[(size_t)i * 64 + lane];  // self term (pre-scaled)
    float ax = bf_lo(v), ay = bf_hi(v);

    for (int base = e0; base < e1; base += 64) {
        int m = e1 - base; if (m > 64) m = 64;
        int cvn = cv;
        if (base + 64 < e1) cvn = colv[base + 64 + lane];   // prefetch next window
        int j = 0;
        for (; j + 7 < m; j += 8) {
            int s0 = __shfl(cv, j),     s1 = __shfl(cv, j + 1);
            int s2 = __shfl(cv, j + 2), s3 = __shfl(cv, j + 3);
            int s4 = __shfl(cv, j + 4), s5 = __shfl(cv, j + 5);
            int s6 = __shfl(cv, j + 6), s7 = __shfl(cv, j + 7);
            unsigned int u0 = gIn[(size_t)s0 * 64 + lane];
            unsigned int u1 = gIn[(size_t)s1 * 64 + lane];
            unsigned int u2 = gIn[(size_t)s2 * 64 + lane];
            unsigned int u3 = gIn[(size_t)s3 * 64 + lane];
            unsigned int u4 = gIn[(size_t)s4 * 64 + lane];
            unsigned int u5 = gIn[(size_t)s5 * 64 + lane];
            unsigned int u6 = gIn[(size_t)s6 * 64 + lane];
            unsigned int u7 = gIn[(size_t)s7 * 64 + lane];
            ax += bf_lo(u0); ay += bf_hi(u0);
            ax += bf_lo(u1); ay += bf_hi(u1);
            ax += bf_lo(u2); ay += bf_hi(u2);
            ax += bf_lo(u3); ay += bf_hi(u3);
            ax += bf_lo(u4); ay += bf_hi(u4);
            ax += bf_lo(u5); ay += bf_hi(u5);
            ax += bf_lo(u6); ay += bf_hi(u6);
            ax += bf_lo(u7); ay += bf_hi(u7);
        }
        for (; j + 3 < m; j += 4) {
            int s0 = __shfl(cv, j),     s1 = __shfl(cv, j + 1);
            int s2 = __shfl(cv, j + 2), s3 = __shfl(cv, j + 3);
            unsigned int u0 = gIn[(size_t)s0 * 64 + lane];
            unsigned int u1 = gIn[(size_t)s1 * 64 + lane];
            unsigned int u2 = gIn[(size_t)s2 * 64 + lane];
            unsigned int u3 = gIn[(size_t)s3 * 64 + lane];
            ax += bf_lo(u0); ay += bf_hi(u0);
            ax += bf_lo(u1); ay += bf_hi(u1);
            ax += bf_lo(u2); ay += bf_hi(u2);
            ax += bf_lo(u3); ay += bf_hi(u3);
        }
        for (; j < m; ++j) {
            int s0 = __shfl(cv, j);
            unsigned int u0 = gIn[(size_t)s0 * 64 + lane];
            ax += bf_lo(u0); ay += bf_hi(u0);
        }
        cv = cvn;
    }
    gOut[(size_t)i * 64 + lane] = pack_bf2(di * ax, di * ay);
}

// ---------------- MFMA matmul (layers 2,3): g_out = bf16(dinv * relu(A @ WT^T + b)) ---

__global__ __launch_bounds__(256) void k_mmx(const unsigned int* __restrict__ gIn,
                                             const unsigned short* __restrict__ WTg,
                                             const float* __restrict__ bias,
                                             const float* __restrict__ dinv,
                                             unsigned int* __restrict__ outg) {
    __shared__ unsigned short sbuf[128 * 136];   // WT (stride 136), reused as Cs (stride 132)
    int t = threadIdx.x;
    // coalesced copy: 16384 shorts, 8 per thread per iter (uint4)
    for (int i = t * 8; i < 128 * 128; i += 256 * 8) {
        int n = i >> 7, k = i & 127;
        uint4 val = *(const uint4*)(WTg + i);
        *(uint4*)(sbuf + n * 136 + k) = val;
    }

    int lane = t & 63, wave = t >> 6;
    int m = lane & 15, quad = lane >> 4;
    int nodeBase = blockIdx.x * 128 + wave * 32;
    const short* gs = (const short*)gIn;

    float bi[8];
    #pragma unroll
    for (int nt = 0; nt < 8; ++nt) bi[nt] = bias[nt * 16 + m];

    f32x4 acc[2][8];
    #pragma unroll
    for (int gi = 0; gi < 2; ++gi)
        #pragma unroll
        for (int nt = 0; nt < 8; ++nt)
            acc[gi][nt] = (f32x4){0.f, 0.f, 0.f, 0.f};

    __syncthreads();

    #pragma unroll
    for (int kc = 0; kc < 4; ++kc) {
        bf16x8 ah[2];
        #pragma unroll
        for (int gi = 0; gi < 2; ++gi) {
            int node = nodeBase + gi * 16 + m;
            bf16x8 h = {0, 0, 0, 0, 0, 0, 0, 0};
            if (node < N_NODES)
                h = *(const bf16x8*)(gs + (size_t)node * 128 + kc * 32 + quad * 8);
            ah[gi] = h;
        }
        #pragma unroll
        for (int nt = 0; nt < 8; ++nt) {
            bf16x8 b = *(const bf16x8*)(sbuf + (nt * 16 + m) * 136 + kc * 32 + quad * 8);
            #pragma unroll
            for (int gi = 0; gi < 2; ++gi)
                acc[gi][nt] = __builtin_amdgcn_mfma_f32_16x16x32_bf16(ah[gi], b, acc[gi][nt], 0, 0, 0);
        }
    }

    __syncthreads();
    #pragma unroll
    for (int gi = 0; gi < 2; ++gi)
        #pragma unroll
        for (int r = 0; r < 4; ++r) {
            int nl = wave * 32 + gi * 16 + quad * 4 + r;
            int node = blockIdx.x * 128 + nl;
            float di = (node < N_NODES) ? dinv[node] : 0.f;
            #pragma unroll
            for (int nt = 0; nt < 8; ++nt) {
                float vv = acc[gi][nt][r] + bi[nt];
                sbuf[nl * 132 + nt * 16 + m] = (unsigned short)f2bf_rne(di * fmaxf(vv, 0.f));
            }
        }
    __syncthreads();
    for (int i = t; i < 128 * 32; i += 256) {
        int nl = i >> 5, p = i & 31;
        int node = blockIdx.x * 128 + nl;
        if (node < N_NODES) {
            uint2 val = *(const uint2*)(sbuf + nl * 132 + p * 4);
            *(uint2*)&outg[(size_t)node * 64 + p * 2] = val;
        }
    }
}

// ---------------- layer-4 pushdown: p[n] = gs[n] @ Wc (2-dim), fp32 ----------------
// (A'G)Wc == A'(G Wc): project to 2 dims BEFORE the last aggregation, shrinking the
// gather buffer 25.6 MB -> 800 KB (L2-resident; kills the 192 MB compulsory fetch).

__global__ __launch_bounds__(256) void k_proj(const unsigned int* __restrict__ gIn,
                                              const float* __restrict__ Wc,
                                              float2* __restrict__ ps) {
    int wid = (blockIdx.x * blockDim.x + threadIdx.x) >> 6;
    int lane = threadIdx.x & 63;
    unsigned int u = gIn[(size_t)wid * 64 + lane];     // features 2l (lo), 2l+1 (hi)
    float4 w = *(const float4*)&Wc[lane * 4];          // W[2l][0..1], W[2l+1][0..1]
    float p0 = bf_lo(u) * w.x + bf_hi(u) * w.z;
    float p1 = bf_lo(u) * w.y + bf_hi(u) * w.w;
    #pragma unroll
    for (int s = 1; s < 64; s <<= 1) {
        p0 += __shfl_xor(p0, s);
        p1 += __shfl_xor(p1, s);
    }
    if (lane == 0) { float2 o; o.x = p0; o.y = p1; ps[wid] = o; }
}

// ---------------- layer-4 aggregation + pool on 2-dim vectors ----------------
// out2_n = dinv_n*(p_n + sum_{s in N(n)} p_s); pooled2[batch[n]] += out2_n.
// 16 lanes per node; ps is L2-resident (800 KB).

__global__ __launch_bounds__(256) void k_agg2(const float2* __restrict__ ps,
                                              const int* __restrict__ rowptr,
                                              const int* __restrict__ col,
                                              const float* __restrict__ dinv,
                                              const int* __restrict__ batch,
                                              float* __restrict__ pooled2) {
    int t = threadIdx.x;
    int node = (blockIdx.x * 256 + t) >> 4;       // 6250 blocks * 16 nodes = N_NODES
    int r = t & 15;
    int e0 = rowptr[node], e1 = rowptr[node + 1];
    float a0 = 0.f, a1 = 0.f;
    for (int e = e0 + r; e < e1; e += 16) {
        int s = col[e];
        float2 pv = ps[s];
        a0 += pv.x; a1 += pv.y;
    }
    #pragma unroll
    for (int sh = 1; sh < 16; sh <<= 1) {
        a0 += __shfl_xor(a0, sh);
        a1 += __shfl_xor(a1, sh);
    }
    if (r == 0) {
        float2 pn = ps[node];
        float di = dinv[node];
        a0 = di * (a0 + pn.x);
        a1 = di * (a1 + pn.y);
        int g = batch[node];
        atomicAdd(&pooled2[g * 2], a0);
        atomicAdd(&pooled2[g * 2 + 1], a1);
    }
}

// ---------------- head: mean + bias (Wc already applied upstream) ----------------

__global__ void k_head2(const float* __restrict__ pooled2, const int* __restrict__ batch,
                        const float* __restrict__ bc, const float* __restrict__ blin,
                        float* __restrict__ out) {
    int g = blockIdx.x * 256 + threadIdx.x;
    if (g >= NG) return;
    int lo = 0, hi = N_NODES;
    while (lo < hi) { int mid = (lo + hi) >> 1; if (batch[mid] < g) lo = mid + 1; else hi = mid; }
    int start = lo;
    hi = N_NODES;
    while (lo < hi) { int mid = (lo + hi) >> 1; if (batch[mid] < g + 1) lo = mid + 1; else hi = mid; }
    int cnt = lo - start;
    if (cnt > 0) {
        float invc = 1.0f / (float)cnt;
        out[g * 2]     = pooled2[g * 2] * invc + bc[0];
        out[g * 2 + 1] = pooled2[g * 2 + 1] * invc + bc[1];
    } else {
        out[g * 2]     = blin[0];
        out[g * 2 + 1] = blin[1];
    }
}

// ---------------- launcher ----------------

extern "C" void kernel_launch(void* const* d_in, const int* in_sizes, int n_in,
                              void* d_out, int out_size, void* d_ws, size_t ws_size,
                              hipStream_t stream) {
    const float* x    = (const float*)d_in[0];
    const int*   eidx = (const int*)d_in[1];
    const int*   batch= (const int*)d_in[2];
    const float* W1   = (const float*)d_in[3];
    const float* b1   = (const float*)d_in[4];
    const float* W2   = (const float*)d_in[5];
    const float* b2   = (const float*)d_in[6];
    const float* W3   = (const float*)d_in[7];
    const float* b3   = (const float*)d_in[8];
    const float* W4   = (const float*)d_in[9];
    const float* b4   = (const float*)d_in[10];
    const float* Wlin = (const float*)d_in[11];
    const float* blin = (const float*)d_in[12];
    float* out = (float*)d_out;

    // workspace carve-up (256B aligned)
    char* ws = (char*)d_ws;
    size_t off = 0;
    auto carve = [&](size_t bytes) { char* p = ws + off; off = (off + bytes + 255) & ~(size_t)255; return p; };
    int*   rowptr    = (int*)carve((size_t)(N_NODES + 1) * 4);
    float* dinv      = (float*)carve((size_t)N_NODES * 4);
    int*   col       = (int*)carve((size_t)E_EDGES * 4);    // k_aggW/k_l1 over-read <=63 ints into ebuf: safe
    unsigned int* ebuf = (unsigned int*)carve((size_t)E_EDGES * 4);
    int*   table     = (int*)carve((size_t)TLEN * 4);
    int*   partial   = (int*)carve((size_t)NCH * 4);
    int*   bucketBase= (int*)carve((size_t)(NBUCK + 1) * 4);
    float* xs        = (float*)carve((size_t)N_NODES * 8 * 4);   // 3.2 MB pre-scaled x (pad 8)
    unsigned int* gA = (unsigned int*)carve((size_t)N_NODES * 64 * 4);   // 25.6 MB bf16 buffer
    unsigned int* gB = (unsigned int*)carve((size_t)N_NODES * 64 * 4);   // 25.6 MB bf16 buffer
    float2* ps       = (float2*)carve((size_t)N_NODES * 8);      // 800 KB projected 2-dim
    float* pooled2   = (float*)carve((size_t)NG * 2 * 4);
    float* Wc        = (float*)carve((size_t)HID * 2 * 4);
    float* bc        = (float*)carve(2 * 4);
    unsigned short* WT2 = (unsigned short*)carve((size_t)HID * HID * 2);
    unsigned short* WT3 = (unsigned short*)carve((size_t)HID * HID * 2);
    (void)ws_size; (void)n_in; (void)in_sizes; (void)out_size;

    const int BLK = 256;

    // CSR hist + Wc fold + pooled2 zero + WT2/WT3 conversion (single fused dispatch)
    k_hist2<<<NBLK_SC + 129, BLK, 0, stream>>>(eidx, table, W4, b4, Wlin, blin,
                                               Wc, bc, pooled2, W2, W3, WT2, WT3);
    k_blocksum<<<NCH, BLK, 0, stream>>>(table, partial);
    k_scan_blk<<<1, 256, 0, stream>>>(partial, bucketBase, rowptr);
    k_scan_final<<<NCH, 1024, 0, stream>>>(table, partial, bucketBase);
    k_scatter2<<<NBLK_SC, BLK, 0, stream>>>(eidx, table, ebuf);
    k_bucket<<<NBUCK, BLK, 0, stream>>>(ebuf, bucketBase, rowptr, dinv, col, x, xs);

    // layer 1 (fused agg + matmul), output pre-scaled by dinv
    k_l1<<<L1_GRID, BLK, 0, stream>>>(xs, W1, b1, rowptr, col, dinv, gA);

    // layer 2: a2 = A' g1 -> MFMA mm (pre-scaled out) -> g2
    k_aggW<<<AGGW_GRID, BLK, 0, stream>>>(gA, gB, rowptr, col, dinv);
    k_mmx<<<MMX_GRID, BLK, 0, stream>>>(gB, WT2, b2, dinv, gA);
    // layer 3: a3 = A' g2 -> MFMA mm (pre-scaled out) -> g3
    k_aggW<<<AGGW_GRID, BLK, 0, stream>>>(gA, gB, rowptr, col, dinv);
    k_mmx<<<MMX_GRID, BLK, 0, stream>>>(gB, WT3, b3, dinv, gA);

    // layer 4 pushdown: project to 2 dims, aggregate tiny vectors, pool
    k_proj<<<PROJ_GRID, BLK, 0, stream>>>(gA, Wc, ps);
    k_agg2<<<AGG2_GRID, BLK, 0, stream>>>(ps, rowptr, col, dinv, batch, pooled2);
    k_head2<<<2, BLK, 0, stream>>>(pooled2, batch, bc, blin, out);
}

// Round 7
// 377.160 us; speedup vs baseline: 1.3427x; 1.3427x over previous
//
#include <hip/hip_runtime.h>
#include <hip/hip_bf16.h>

#define N_NODES 100000
#define E_EDGES 1600000
#define NG 512
#define FIN 7
#define HID 128
#define NBUCK 782          // ceil(N_NODES/128), bucket = 128 consecutive dst nodes
#define NBLK_SC 256        // partition blocks (each owns a contiguous edge chunk)
#define CHUNK 6250         // E_EDGES / NBLK_SC (exact)
#define TLEN (NBUCK * NBLK_SC)   // 200192 table entries
#define NCH 196            // ceil(TLEN/1024) scan chunks
#define MMX_GRID 782       // ceil(N_NODES/128)
#define AGGW_GRID 25000    // N_NODES waves, 4 waves per block
#define L1_GRID 25000      // N_NODES / 4 nodes per block (1 node per wave)
#define PROJ_GRID 25000    // N_NODES waves, 4 waves per block
#define AGG2_GRID 6250     // N_NODES / 16 nodes per block (16 lanes per node)

typedef __attribute__((ext_vector_type(8))) short bf16x8;
typedef __attribute__((ext_vector_type(4))) float f32x4;

// bf16 helpers: decode packed pair, encode with RNE
__device__ __forceinline__ float bf_lo(unsigned int u) { return __uint_as_float(u << 16); }
__device__ __forceinline__ float bf_hi(unsigned int u) { return __uint_as_float(u & 0xffff0000u); }
__device__ __forceinline__ unsigned int f2bf_rne(float f) {
    unsigned int x = __float_as_uint(f);
    return (x + 0x7fffu + ((x >> 16) & 1u)) >> 16;   // finite inputs only
}
__device__ __forceinline__ unsigned int pack_bf2(float lo, float hi) {
    return f2bf_rne(lo) | (f2bf_rne(hi) << 16);
}

// ------ CSR hist (0..255) + [Wc fold + bc] (256) + WT2/WT3 (257..384)

__global__ __launch_bounds__(256) void k_hist2(const int* __restrict__ eidx,
                                               int* __restrict__ table,
                                               const float* __restrict__ W4,
                                               const float* __restrict__ b4,
                                               const float* __restrict__ Wlin,
                                               const float* __restrict__ blin,
                                               float* __restrict__ Wc,
                                               float* __restrict__ bc,
                                               const float* __restrict__ W2,
                                               const float* __restrict__ W3,
                                               unsigned short* __restrict__ WT2,
                                               unsigned short* __restrict__ WT3) {
    __shared__ int h[NBUCK];
    int blk = blockIdx.x, t = threadIdx.x;
    if (blk >= NBLK_SC) {
        int r = blk - NBLK_SC;
        if (r == 0) {
            int k = t >> 1, o = t & 1;
            float acc = 0.f;
            for (int j = 0; j < HID; ++j) acc += W4[k * HID + j] * Wlin[j * 2 + o];
            Wc[k * 2 + o] = acc;
            if (k == 0) {
                float b = blin[o];
                for (int j = 0; j < HID; ++j) b += b4[j] * Wlin[j * 2 + o];
                bc[o] = b;
            }
        } else if (r < 65) {    // WT2: transpose+convert, 64 blocks x 256 = 16384 elems
            int idx = (r - 1) * 256 + t;
            int k = idx >> 7, n = idx & 127;
            WT2[n * 128 + k] = (unsigned short)f2bf_rne(W2[idx]);
        } else {                // WT3
            int idx = (r - 65) * 256 + t;
            int k = idx >> 7, n = idx & 127;
            WT3[n * 128 + k] = (unsigned short)f2bf_rne(W3[idx]);
        }
        return;
    }
    for (int i = t; i < NBUCK; i += 256) h[i] = 0;
    __syncthreads();
    int e0 = blk * CHUNK, e1 = e0 + CHUNK;
    for (int e = e0 + t; e < e1; e += 256)
        atomicAdd(&h[eidx[E_EDGES + e] >> 7], 1);
    __syncthreads();
    for (int i = t; i < NBUCK; i += 256)
        table[i * NBLK_SC + blk] = h[i];
}

__global__ void k_blocksum(const int* __restrict__ table, int* __restrict__ partial) {
    __shared__ int s[256];
    int b = blockIdx.x, t = threadIdx.x;
    int base = b * 1024;
    int sum = 0;
    for (int i = t; i < 1024; i += 256) {
        int idx = base + i;
        sum += (idx < TLEN) ? table[idx] : 0;
    }
    s[t] = sum; __syncthreads();
    for (int st = 128; st > 0; st >>= 1) {
        if (t < st) s[t] += s[t + st];
        __syncthreads();
    }
    if (t == 0) partial[b] = s[0];
}

// parallel exclusive scan of the 196 chunk sums (one 256-thread block)
__global__ void k_scan_blk(int* __restrict__ partial, int* __restrict__ bucketBase,
                           int* __restrict__ rowptr) {
    __shared__ int s[256];
    int t = threadIdx.x;
    int v = (t < NCH) ? partial[t] : 0;
    s[t] = v; __syncthreads();
    for (int st = 1; st < 256; st <<= 1) {
        int a = (t >= st) ? s[t - st] : 0;
        __syncthreads();
        s[t] += a;
        __syncthreads();
    }
    if (t < NCH) partial[t] = s[t] - v;   // exclusive
    if (t == 0) { bucketBase[NBUCK] = E_EDGES; rowptr[N_NODES] = E_EDGES; }
}

__global__ void k_scan_final(int* __restrict__ table, const int* __restrict__ partial,
                             int* __restrict__ bucketBase) {
    __shared__ int s[1024];
    int b = blockIdx.x, t = threadIdx.x;
    int idx = b * 1024 + t;
    int v = (idx < TLEN) ? table[idx] : 0;
    s[t] = v; __syncthreads();
    for (int st = 1; st < 1024; st <<= 1) {
        int add = (t >= st) ? s[t - st] : 0;
        __syncthreads();
        s[t] += add;
        __syncthreads();
    }
    if (idx < TLEN) {
        int ex = partial[b] + s[t] - v;   // exclusive
        table[idx] = ex;
        if ((idx & (NBLK_SC - 1)) == 0) bucketBase[idx / NBLK_SC] = ex;
    }
}

__global__ __launch_bounds__(256) void k_scatter2(const int* __restrict__ eidx,
                                                  const int* __restrict__ table,
                                                  unsigned int* __restrict__ ebuf) {
    __shared__ int loff[NBUCK];
    int blk = blockIdx.x, t = threadIdx.x;
    for (int i = t; i < NBUCK; i += 256) loff[i] = table[i * NBLK_SC + blk];
    __syncthreads();
    int e0 = blk * CHUNK, e1 = e0 + CHUNK;
    for (int e = e0 + t; e < e1; e += 256) {
        int s = eidx[e];
        int d = eidx[E_EDGES + e];
        int p = atomicAdd(&loff[d >> 7], 1);
        ebuf[p] = ((unsigned int)(d & 127) << 17) | (unsigned int)s;
    }
}

// col[] stores plain src node id. Also emits xs[n][0..7] = dinv[n]*x[n] (pad 0) for k_l1.
__global__ __launch_bounds__(256) void k_bucket(const unsigned int* __restrict__ ebuf,
                                                const int* __restrict__ bucketBase,
                                                int* __restrict__ rowptr,
                                                float* __restrict__ dinv,
                                                int* __restrict__ col,
                                                const float* __restrict__ x,
                                                float* __restrict__ xs) {
    __shared__ int scnt[128], soff[128], scur[128];
    int b = blockIdx.x, t = threadIdx.x;
    int bbase = bucketBase[b], bend = bucketBase[b + 1];
    if (t < 128) { scnt[t] = 0; scur[t] = 0; }
    __syncthreads();
    for (int e = bbase + t; e < bend; e += 256) {
        unsigned int rec = ebuf[e];
        atomicAdd(&scnt[rec >> 17], 1);
    }
    __syncthreads();
    if (t < 128) soff[t] = scnt[t];
    __syncthreads();
    for (int st = 1; st < 128; st <<= 1) {
        int a = (t < 128 && t >= st) ? soff[t - st] : 0;
        __syncthreads();
        if (t < 128) soff[t] += a;
        __syncthreads();
    }
    float dval = 0.f;
    if (t < 128) {
        int ex = soff[t] - scnt[t];
        int node = b * 128 + t;
        if (node < N_NODES) {
            rowptr[node] = bbase + ex;
            dval = rsqrtf((float)(scnt[t] + 1));   // +1 self-loop
            dinv[node] = dval;
        }
        soff[t] = ex;
    }
    __syncthreads();
    for (int e = bbase + t; e < bend; e += 256) {
        unsigned int rec = ebuf[e];
        int dl = rec >> 17;
        int s = rec & 0x1FFFF;
        int p = bbase + soff[dl] + atomicAdd(&scur[dl], 1);
        col[p] = s;
    }
    // pre-scaled padded input rows for k_l1 (threads >=128 have exited the loop)
    if (t < 128) {
        int node = b * 128 + t;
        if (node < N_NODES) {
            float4 v0, v1;
            v0.x = dval * x[node * 7 + 0];
            v0.y = dval * x[node * 7 + 1];
            v0.z = dval * x[node * 7 + 2];
            v0.w = dval * x[node * 7 + 3];
            v1.x = dval * x[node * 7 + 4];
            v1.y = dval * x[node * 7 + 5];
            v1.z = dval * x[node * 7 + 6];
            v1.w = 0.f;
            *(float4*)&xs[node * 8] = v0;
            *(float4*)&xs[node * 8 + 4] = v1;
        }
    }
}

// ---------------- fused layer 1: g1 = bf16(dinv * relu((A' x) W1 + b1)) ----------------
// One wave per node. Gather phase: 8 lanes per edge (lane = g*8+r), 8 edges per step,
// acc[r] += xs[s][r]. Self term in GROUP 0 ONLY (butterfly sums across groups).

__global__ __launch_bounds__(256) void k_l1(const float* __restrict__ xs,
                                            const float* __restrict__ W1,
                                            const float* __restrict__ b1,
                                            const int* __restrict__ rowptr,
                                            const int* __restrict__ col,
                                            const float* __restrict__ dinv,
                                            unsigned int* __restrict__ g1) {
    __shared__ float w1s[FIN * HID];   // 3.5 KB
    __shared__ float b1s[HID];
    int t = threadIdx.x;
    for (int i = t; i < FIN * HID; i += 256) w1s[i] = W1[i];
    if (t < HID) b1s[t] = b1[t];
    __syncthreads();

    int lane = t & 63, wave = t >> 6;
    int g = lane >> 3, r = lane & 7;
    int node = blockIdx.x * 4 + wave;            // grid exact: 25000*4 = N_NODES
    float di = dinv[node];
    float acc = (g == 0) ? xs[node * 8 + r] : 0.f;   // self term once (group 0 only)
    int e0 = rowptr[node], e1 = rowptr[node + 1];

    for (int base = e0; base < e1; base += 64) {
        int m = e1 - base; if (m > 64) m = 64;
        int cv = col[base + lane];               // over-read past e1 safe (ebuf region)
        int j = 0;
        for (; j + 8 <= m; j += 8) {
            int s = __shfl(cv, j + g);
            acc += xs[s * 8 + r];
        }
        if (j < m) {
            int jg = j + g;
            int idx = (jg < m) ? jg : j;         // j < m here, so idx always valid
            int s = __shfl(cv, idx);
            float u = xs[s * 8 + r];
            if (jg < m) acc += u;
        }
    }
    // reduce across the 8 edge-groups: every lane gets the full sum for feature r
    acc += __shfl_xor(acc, 8);
    acc += __shfl_xor(acc, 16);
    acc += __shfl_xor(acc, 32);
    acc *= di;                                   // outer dinv_i of the symmetric norm

    // broadcast the 7 aggregated features, project: lane -> outputs 2l, 2l+1
    float av[FIN];
    #pragma unroll
    for (int k = 0; k < FIN; ++k) av[k] = __shfl(acc, k);
    float2 bb = *(const float2*)&b1s[2 * lane];
    float acc0 = bb.x, acc1 = bb.y;
    #pragma unroll
    for (int k = 0; k < FIN; ++k) {
        float2 w = *(const float2*)&w1s[k * HID + 2 * lane];
        acc0 += av[k] * w.x;
        acc1 += av[k] * w.y;
    }
    g1[(size_t)node * 64 + lane] = pack_bf2(di * fmaxf(acc0, 0.f), di * fmaxf(acc1, 0.f));
}

// ---------------- aggregation: wave/node, pre-scaled rows, prefetched windows --------
// At the compulsory-fetch floor (8 XCDs x 25.6 MB buffer ~= 192 MB measured): leave as is.

__global__ __launch_bounds__(256) void k_aggW(const unsigned int* __restrict__ gIn,
                                              unsigned int* __restrict__ gOut,
                                              const int* __restrict__ rowptr,
                                              const int* __restrict__ colv,
                                              const float* __restrict__ dinv) {
    int wid = (blockIdx.x * blockDim.x + threadIdx.x) >> 6;
    int lane = threadIdx.x & 63;
    if (wid >= N_NODES) return;
    int i = wid;
    float di = dinv[i];
    int e0 = rowptr[i], e1 = rowptr[i + 1];
    int cv = colv[e0 + lane];                     // over-read past e1 is safe/unused
    unsigned int v = gIn[(size_t)i * 64 + lane];  // self term (pre-scaled)
    float ax = bf_lo(v), ay = bf_hi(v);

    for (int base = e0; base < e1; base += 64) {
        int m = e1 - base; if (m > 64) m = 64;
        int cvn = cv;
        if (base + 64 < e1) cvn = colv[base + 64 + lane];   // prefetch next window
        int j = 0;
        for (; j + 7 < m; j += 8) {
            int s0 = __shfl(cv, j),     s1 = __shfl(cv, j + 1);
            int s2 = __shfl(cv, j + 2), s3 = __shfl(cv, j + 3);
            int s4 = __shfl(cv, j + 4), s5 = __shfl(cv, j + 5);
            int s6 = __shfl(cv, j + 6), s7 = __shfl(cv, j + 7);
            unsigned int u0 = gIn[(size_t)s0 * 64 + lane];
            unsigned int u1 = gIn[(size_t)s1 * 64 + lane];
            unsigned int u2 = gIn[(size_t)s2 * 64 + lane];
            unsigned int u3 = gIn[(size_t)s3 * 64 + lane];
            unsigned int u4 = gIn[(size_t)s4 * 64 + lane];
            unsigned int u5 = gIn[(size_t)s5 * 64 + lane];
            unsigned int u6 = gIn[(size_t)s6 * 64 + lane];
            unsigned int u7 = gIn[(size_t)s7 * 64 + lane];
            ax += bf_lo(u0); ay += bf_hi(u0);
            ax += bf_lo(u1); ay += bf_hi(u1);
            ax += bf_lo(u2); ay += bf_hi(u2);
            ax += bf_lo(u3); ay += bf_hi(u3);
            ax += bf_lo(u4); ay += bf_hi(u4);
            ax += bf_lo(u5); ay += bf_hi(u5);
            ax += bf_lo(u6); ay += bf_hi(u6);
            ax += bf_lo(u7); ay += bf_hi(u7);
        }
        for (; j + 3 < m; j += 4) {
            int s0 = __shfl(cv, j),     s1 = __shfl(cv, j + 1);
            int s2 = __shfl(cv, j + 2), s3 = __shfl(cv, j + 3);
            unsigned int u0 = gIn[(size_t)s0 * 64 + lane];
            unsigned int u1 = gIn[(size_t)s1 * 64 + lane];
            unsigned int u2 = gIn[(size_t)s2 * 64 + lane];
            unsigned int u3 = gIn[(size_t)s3 * 64 + lane];
            ax += bf_lo(u0); ay += bf_hi(u0);
            ax += bf_lo(u1); ay += bf_hi(u1);
            ax += bf_lo(u2); ay += bf_hi(u2);
            ax += bf_lo(u3); ay += bf_hi(u3);
        }
        for (; j < m; ++j) {
            int s0 = __shfl(cv, j);
            unsigned int u0 = gIn[(size_t)s0 * 64 + lane];
            ax += bf_lo(u0); ay += bf_hi(u0);
        }
        cv = cvn;
    }
    gOut[(size_t)i * 64 + lane] = pack_bf2(di * ax, di * ay);
}

// ---------------- MFMA matmul (layers 2,3): g_out = bf16(dinv * relu(A @ WT^T + b)) ---

__global__ __launch_bounds__(256) void k_mmx(const unsigned int* __restrict__ gIn,
                                             const unsigned short* __restrict__ WTg,
                                             const float* __restrict__ bias,
                                             const float* __restrict__ dinv,
                                             unsigned int* __restrict__ outg) {
    __shared__ unsigned short sbuf[128 * 136];   // WT (stride 136), reused as Cs (stride 132)
    int t = threadIdx.x;
    // coalesced copy: 16384 shorts, 8 per thread per iter (uint4)
    for (int i = t * 8; i < 128 * 128; i += 256 * 8) {
        int n = i >> 7, k = i & 127;
        uint4 val = *(const uint4*)(WTg + i);
        *(uint4*)(sbuf + n * 136 + k) = val;
    }

    int lane = t & 63, wave = t >> 6;
    int m = lane & 15, quad = lane >> 4;
    int nodeBase = blockIdx.x * 128 + wave * 32;
    const short* gs = (const short*)gIn;

    float bi[8];
    #pragma unroll
    for (int nt = 0; nt < 8; ++nt) bi[nt] = bias[nt * 16 + m];

    f32x4 acc[2][8];
    #pragma unroll
    for (int gi = 0; gi < 2; ++gi)
        #pragma unroll
        for (int nt = 0; nt < 8; ++nt)
            acc[gi][nt] = (f32x4){0.f, 0.f, 0.f, 0.f};

    __syncthreads();

    #pragma unroll
    for (int kc = 0; kc < 4; ++kc) {
        bf16x8 ah[2];
        #pragma unroll
        for (int gi = 0; gi < 2; ++gi) {
            int node = nodeBase + gi * 16 + m;
            bf16x8 h = {0, 0, 0, 0, 0, 0, 0, 0};
            if (node < N_NODES)
                h = *(const bf16x8*)(gs + (size_t)node * 128 + kc * 32 + quad * 8);
            ah[gi] = h;
        }
        #pragma unroll
        for (int nt = 0; nt < 8; ++nt) {
            bf16x8 b = *(const bf16x8*)(sbuf + (nt * 16 + m) * 136 + kc * 32 + quad * 8);
            #pragma unroll
            for (int gi = 0; gi < 2; ++gi)
                acc[gi][nt] = __builtin_amdgcn_mfma_f32_16x16x32_bf16(ah[gi], b, acc[gi][nt], 0, 0, 0);
        }
    }

    __syncthreads();
    #pragma unroll
    for (int gi = 0; gi < 2; ++gi)
        #pragma unroll
        for (int r = 0; r < 4; ++r) {
            int nl = wave * 32 + gi * 16 + quad * 4 + r;
            int node = blockIdx.x * 128 + nl;
            float di = (node < N_NODES) ? dinv[node] : 0.f;
            #pragma unroll
            for (int nt = 0; nt < 8; ++nt) {
                float vv = acc[gi][nt][r] + bi[nt];
                sbuf[nl * 132 + nt * 16 + m] = (unsigned short)f2bf_rne(di * fmaxf(vv, 0.f));
            }
        }
    __syncthreads();
    for (int i = t; i < 128 * 32; i += 256) {
        int nl = i >> 5, p = i & 31;
        int node = blockIdx.x * 128 + nl;
        if (node < N_NODES) {
            uint2 val = *(const uint2*)(sbuf + nl * 132 + p * 4);
            *(uint2*)&outg[(size_t)node * 64 + p * 2] = val;
        }
    }
}

// ---------------- layer-4 pushdown: p[n] = gs[n] @ Wc (2-dim), fp32 ----------------
// (A'G)Wc == A'(G Wc): project to 2 dims BEFORE the last aggregation, shrinking the
// gather buffer 25.6 MB -> 800 KB (L2-resident; kills the 192 MB compulsory fetch).

__global__ __launch_bounds__(256) void k_proj(const unsigned int* __restrict__ gIn,
                                              const float* __restrict__ Wc,
                                              float2* __restrict__ ps) {
    int wid = (blockIdx.x * blockDim.x + threadIdx.x) >> 6;
    int lane = threadIdx.x & 63;
    unsigned int u = gIn[(size_t)wid * 64 + lane];     // features 2l (lo), 2l+1 (hi)
    float4 w = *(const float4*)&Wc[lane * 4];          // W[2l][0..1], W[2l+1][0..1]
    float p0 = bf_lo(u) * w.x + bf_hi(u) * w.z;
    float p1 = bf_lo(u) * w.y + bf_hi(u) * w.w;
    #pragma unroll
    for (int s = 1; s < 64; s <<= 1) {
        p0 += __shfl_xor(p0, s);
        p1 += __shfl_xor(p1, s);
    }
    if (lane == 0) { float2 o; o.x = p0; o.y = p1; ps[wid] = o; }
}

// ---------------- layer-4 aggregation on 2-dim vectors — NO ATOMICS ----------------
// out2_n = dinv_n*(p_n + sum_{s in N(n)} p_s), written per node. The R6 version fused
// the pool via global fp32 atomics to 1024 addresses with a SORTED batch -> massive
// same-address RMW serialization (140 us). Pure write here; pooling moved to k_pool2.

__global__ __launch_bounds__(256) void k_agg2(const float2* __restrict__ ps,
                                              const int* __restrict__ rowptr,
                                              const int* __restrict__ col,
                                              const float* __restrict__ dinv,
                                              float2* __restrict__ out2) {
    int t = threadIdx.x;
    int node = (blockIdx.x * 256 + t) >> 4;       // 6250 blocks * 16 nodes = N_NODES
    int r = t & 15;
    int e0 = rowptr[node], e1 = rowptr[node + 1];
    float a0 = 0.f, a1 = 0.f;
    for (int e = e0 + r; e < e1; e += 16) {
        int s = col[e];
        float2 pv = ps[s];
        a0 += pv.x; a1 += pv.y;
    }
    #pragma unroll
    for (int sh = 1; sh < 16; sh <<= 1) {
        a0 += __shfl_xor(a0, sh);
        a1 += __shfl_xor(a1, sh);
    }
    if (r == 0) {
        float2 pn = ps[node];
        float di = dinv[node];
        float2 o;
        o.x = di * (a0 + pn.x);
        o.y = di * (a1 + pn.y);
        out2[node] = o;
    }
}

// ---------------- pool + head: one wave per graph, coalesced reduce, no atomics ------

__global__ __launch_bounds__(256) void k_pool2(const float2* __restrict__ out2,
                                               const int* __restrict__ batch,
                                               const float* __restrict__ bc,
                                               const float* __restrict__ blin,
                                               float* __restrict__ out) {
    int g = (blockIdx.x * blockDim.x + threadIdx.x) >> 6;
    int lane = threadIdx.x & 63;
    if (g >= NG) return;
    int lo = 0, hi = N_NODES;
    while (lo < hi) { int mid = (lo + hi) >> 1; if (batch[mid] < g) lo = mid + 1; else hi = mid; }
    int start = lo;
    hi = N_NODES;
    while (lo < hi) { int mid = (lo + hi) >> 1; if (batch[mid] < g + 1) lo = mid + 1; else hi = mid; }
    int end = lo, cnt = end - start;
    float a0 = 0.f, a1 = 0.f;
    for (int n = start + lane; n < end; n += 64) {
        float2 v = out2[n];
        a0 += v.x; a1 += v.y;
    }
    #pragma unroll
    for (int sh = 1; sh < 64; sh <<= 1) {
        a0 += __shfl_xor(a0, sh);
        a1 += __shfl_xor(a1, sh);
    }
    if (lane == 0) {
        if (cnt > 0) {
            float ic = 1.0f / (float)cnt;
            out[g * 2]     = a0 * ic + bc[0];
            out[g * 2 + 1] = a1 * ic + bc[1];
        } else {
            out[g * 2]     = blin[0];
            out[g * 2 + 1] = blin[1];
        }
    }
}

// ---------------- launcher ----------------

extern "C" void kernel_launch(void* const* d_in, const int* in_sizes, int n_in,
                              void* d_out, int out_size, void* d_ws, size_t ws_size,
                              hipStream_t stream) {
    const float* x    = (const float*)d_in[0];
    const int*   eidx = (const int*)d_in[1];
    const int*   batch= (const int*)d_in[2];
    const float* W1   = (const float*)d_in[3];
    const float* b1   = (const float*)d_in[4];
    const float* W2   = (const float*)d_in[5];
    const float* b2   = (const float*)d_in[6];
    const float* W3   = (const float*)d_in[7];
    const float* b3   = (const float*)d_in[8];
    const float* W4   = (const float*)d_in[9];
    const float* b4   = (const float*)d_in[10];
    const float* Wlin = (const float*)d_in[11];
    const float* blin = (const float*)d_in[12];
    float* out = (float*)d_out;

    // workspace carve-up (256B aligned)
    char* ws = (char*)d_ws;
    size_t off = 0;
    auto carve = [&](size_t bytes) { char* p = ws + off; off = (off + bytes + 255) & ~(size_t)255; return p; };
    int*   rowptr    = (int*)carve((size_t)(N_NODES + 1) * 4);
    float* dinv      = (float*)carve((size_t)N_NODES * 4);
    int*   col       = (int*)carve((size_t)E_EDGES * 4);    // k_aggW/k_l1 over-read <=63 ints into ebuf: safe
    unsigned int* ebuf = (unsigned int*)carve((size_t)E_EDGES * 4);
    int*   table     = (int*)carve((size_t)TLEN * 4);
    int*   partial   = (int*)carve((size_t)NCH * 4);
    int*   bucketBase= (int*)carve((size_t)(NBUCK + 1) * 4);
    float* xs        = (float*)carve((size_t)N_NODES * 8 * 4);   // 3.2 MB pre-scaled x (pad 8)
    unsigned int* gA = (unsigned int*)carve((size_t)N_NODES * 64 * 4);   // 25.6 MB bf16 buffer
    unsigned int* gB = (unsigned int*)carve((size_t)N_NODES * 64 * 4);   // 25.6 MB bf16 buffer
    float2* ps       = (float2*)carve((size_t)N_NODES * 8);      // 800 KB projected 2-dim
    float2* out2     = (float2*)carve((size_t)N_NODES * 8);      // 800 KB aggregated 2-dim
    float* Wc        = (float*)carve((size_t)HID * 2 * 4);
    float* bc        = (float*)carve(2 * 4);
    unsigned short* WT2 = (unsigned short*)carve((size_t)HID * HID * 2);
    unsigned short* WT3 = (unsigned short*)carve((size_t)HID * HID * 2);
    (void)ws_size; (void)n_in; (void)in_sizes; (void)out_size;

    const int BLK = 256;

    // CSR hist + Wc fold + WT2/WT3 conversion (single fused dispatch)
    k_hist2<<<NBLK_SC + 129, BLK, 0, stream>>>(eidx, table, W4, b4, Wlin, blin,
                                               Wc, bc, W2, W3, WT2, WT3);
    k_blocksum<<<NCH, BLK, 0, stream>>>(table, partial);
    k_scan_blk<<<1, 256, 0, stream>>>(partial, bucketBase, rowptr);
    k_scan_final<<<NCH, 1024, 0, stream>>>(table, partial, bucketBase);
    k_scatter2<<<NBLK_SC, BLK, 0, stream>>>(eidx, table, ebuf);
    k_bucket<<<NBUCK, BLK, 0, stream>>>(ebuf, bucketBase, rowptr, dinv, col, x, xs);

    // layer 1 (fused agg + matmul), output pre-scaled by dinv
    k_l1<<<L1_GRID, BLK, 0, stream>>>(xs, W1, b1, rowptr, col, dinv, gA);

    // layer 2: a2 = A' g1 -> MFMA mm (pre-scaled out) -> g2
    k_aggW<<<AGGW_GRID, BLK, 0, stream>>>(gA, gB, rowptr, col, dinv);
    k_mmx<<<MMX_GRID, BLK, 0, stream>>>(gB, WT2, b2, dinv, gA);
    // layer 3: a3 = A' g2 -> MFMA mm (pre-scaled out) -> g3
    k_aggW<<<AGGW_GRID, BLK, 0, stream>>>(gA, gB, rowptr, col, dinv);
    k_mmx<<<MMX_GRID, BLK, 0, stream>>>(gB, WT3, b3, dinv, gA);

    // layer 4 pushdown: project to 2 dims, aggregate tiny vectors (no atomics),
    // then one wave per graph pools + applies bias
    k_proj<<<PROJ_GRID, BLK, 0, stream>>>(gA, Wc, ps);
    k_agg2<<<AGG2_GRID, BLK, 0, stream>>>(ps, rowptr, col, dinv, out2);
    k_pool2<<<(NG * 64 + BLK - 1) / BLK, BLK, 0, stream>>>(out2, batch, bc, blin, out);
}

// Round 8
// 360.666 us; speedup vs baseline: 1.4042x; 1.0457x over previous
//
#include <hip/hip_runtime.h>
#include <hip/hip_bf16.h>

#define N_NODES 100000
#define E_EDGES 1600000
#define NG 512
#define FIN 7
#define HID 128
#define NBUCK 782          // ceil(N_NODES/128), bucket = 128 consecutive dst nodes
#define NBLK_SC 256        // partition blocks (each owns a contiguous edge chunk)
#define CHUNK 6250         // E_EDGES / NBLK_SC (exact)
#define TLEN (NBUCK * NBLK_SC)   // 200192 table entries
#define NCH 196            // ceil(TLEN/1024) scan chunks
#define MMX_GRID 782       // ceil(N_NODES/128)
#define AGGW_GRID 25000    // N_NODES waves, 4 waves per block
#define L1_GRID 25000      // N_NODES / 4 nodes per block (1 node per wave)

typedef __attribute__((ext_vector_type(8))) short bf16x8;
typedef __attribute__((ext_vector_type(4))) float f32x4;

// bf16 helpers: decode packed pair, encode with RNE
__device__ __forceinline__ float bf_lo(unsigned int u) { return __uint_as_float(u << 16); }
__device__ __forceinline__ float bf_hi(unsigned int u) { return __uint_as_float(u & 0xffff0000u); }
__device__ __forceinline__ unsigned int f2bf_rne(float f) {
    unsigned int x = __float_as_uint(f);
    return (x + 0x7fffu + ((x >> 16) & 1u)) >> 16;   // finite inputs only
}
__device__ __forceinline__ unsigned int pack_bf2(float lo, float hi) {
    return f2bf_rne(lo) | (f2bf_rne(hi) << 16);
}

// ------ CSR hist (0..255) + [Wc fold + bc] (256) + WT2/WT3 (257..384)

__global__ __launch_bounds__(256) void k_hist2(const int* __restrict__ eidx,
                                               int* __restrict__ table,
                                               const float* __restrict__ W4,
                                               const float* __restrict__ b4,
                                               const float* __restrict__ Wlin,
                                               const float* __restrict__ blin,
                                               float* __restrict__ Wc,
                                               float* __restrict__ bc,
                                               const float* __restrict__ W2,
                                               const float* __restrict__ W3,
                                               unsigned short* __restrict__ WT2,
                                               unsigned short* __restrict__ WT3) {
    __shared__ int h[NBUCK];
    int blk = blockIdx.x, t = threadIdx.x;
    if (blk >= NBLK_SC) {
        int r = blk - NBLK_SC;
        if (r == 0) {
            int k = t >> 1, o = t & 1;
            float acc = 0.f;
            for (int j = 0; j < HID; ++j) acc += W4[k * HID + j] * Wlin[j * 2 + o];
            Wc[k * 2 + o] = acc;
            if (k == 0) {
                float b = blin[o];
                for (int j = 0; j < HID; ++j) b += b4[j] * Wlin[j * 2 + o];
                bc[o] = b;
            }
        } else if (r < 65) {    // WT2: transpose+convert, 64 blocks x 256 = 16384 elems
            int idx = (r - 1) * 256 + t;
            int k = idx >> 7, n = idx & 127;
            WT2[n * 128 + k] = (unsigned short)f2bf_rne(W2[idx]);
        } else {                // WT3
            int idx = (r - 65) * 256 + t;
            int k = idx >> 7, n = idx & 127;
            WT3[n * 128 + k] = (unsigned short)f2bf_rne(W3[idx]);
        }
        return;
    }
    for (int i = t; i < NBUCK; i += 256) h[i] = 0;
    __syncthreads();
    int e0 = blk * CHUNK, e1 = e0 + CHUNK;
    for (int e = e0 + t; e < e1; e += 256)
        atomicAdd(&h[eidx[E_EDGES + e] >> 7], 1);
    __syncthreads();
    for (int i = t; i < NBUCK; i += 256)
        table[i * NBLK_SC + blk] = h[i];
}

__global__ void k_blocksum(const int* __restrict__ table, int* __restrict__ partial) {
    __shared__ int s[256];
    int b = blockIdx.x, t = threadIdx.x;
    int base = b * 1024;
    int sum = 0;
    for (int i = t; i < 1024; i += 256) {
        int idx = base + i;
        sum += (idx < TLEN) ? table[idx] : 0;
    }
    s[t] = sum; __syncthreads();
    for (int st = 128; st > 0; st >>= 1) {
        if (t < st) s[t] += s[t + st];
        __syncthreads();
    }
    if (t == 0) partial[b] = s[0];
}

// table scan; each block redundantly scans the 196 chunk sums in LDS (kills the
// separate 1-block k_scan_blk dispatch).
__global__ void k_scan_final(int* __restrict__ table, const int* __restrict__ partial,
                             int* __restrict__ bucketBase, int* __restrict__ rowptr) {
    __shared__ int s[1024];
    __shared__ int cs[256];
    int b = blockIdx.x, t = threadIdx.x;
    if (t < 256) cs[t] = (t < NCH) ? partial[t] : 0;
    __syncthreads();
    for (int st = 1; st < 256; st <<= 1) {
        int a = (t < 256 && t >= st) ? cs[t - st] : 0;
        __syncthreads();
        if (t < 256) cs[t] += a;
        __syncthreads();
    }
    int chunk_ex = cs[b] - partial[b];             // exclusive chunk offset for this block
    int idx = b * 1024 + t;
    int v = (idx < TLEN) ? table[idx] : 0;
    s[t] = v; __syncthreads();
    for (int st = 1; st < 1024; st <<= 1) {
        int add = (t >= st) ? s[t - st] : 0;
        __syncthreads();
        s[t] += add;
        __syncthreads();
    }
    if (idx < TLEN) {
        int ex = chunk_ex + s[t] - v;   // exclusive
        table[idx] = ex;
        if ((idx & (NBLK_SC - 1)) == 0) bucketBase[idx / NBLK_SC] = ex;
    }
    if (b == 0 && t == 0) { bucketBase[NBUCK] = E_EDGES; rowptr[N_NODES] = E_EDGES; }
}

__global__ __launch_bounds__(256) void k_scatter2(const int* __restrict__ eidx,
                                                  const int* __restrict__ table,
                                                  unsigned int* __restrict__ ebuf) {
    __shared__ int loff[NBUCK];
    int blk = blockIdx.x, t = threadIdx.x;
    for (int i = t; i < NBUCK; i += 256) loff[i] = table[i * NBLK_SC + blk];
    __syncthreads();
    int e0 = blk * CHUNK, e1 = e0 + CHUNK;
    for (int e = e0 + t; e < e1; e += 256) {
        int s = eidx[e];
        int d = eidx[E_EDGES + e];
        int p = atomicAdd(&loff[d >> 7], 1);
        ebuf[p] = ((unsigned int)(d & 127) << 17) | (unsigned int)s;
    }
}

// col[] stores plain src node id. Also emits xs[n][0..7] = dinv[n]*x[n] (pad 0) for k_l1.
__global__ __launch_bounds__(256) void k_bucket(const unsigned int* __restrict__ ebuf,
                                                const int* __restrict__ bucketBase,
                                                int* __restrict__ rowptr,
                                                float* __restrict__ dinv,
                                                int* __restrict__ col,
                                                const float* __restrict__ x,
                                                float* __restrict__ xs) {
    __shared__ int scnt[128], soff[128], scur[128];
    int b = blockIdx.x, t = threadIdx.x;
    int bbase = bucketBase[b], bend = bucketBase[b + 1];
    if (t < 128) { scnt[t] = 0; scur[t] = 0; }
    __syncthreads();
    for (int e = bbase + t; e < bend; e += 256) {
        unsigned int rec = ebuf[e];
        atomicAdd(&scnt[rec >> 17], 1);
    }
    __syncthreads();
    if (t < 128) soff[t] = scnt[t];
    __syncthreads();
    for (int st = 1; st < 128; st <<= 1) {
        int a = (t < 128 && t >= st) ? soff[t - st] : 0;
        __syncthreads();
        if (t < 128) soff[t] += a;
        __syncthreads();
    }
    float dval = 0.f;
    if (t < 128) {
        int ex = soff[t] - scnt[t];
        int node = b * 128 + t;
        if (node < N_NODES) {
            rowptr[node] = bbase + ex;
            dval = rsqrtf((float)(scnt[t] + 1));   // +1 self-loop
            dinv[node] = dval;
        }
        soff[t] = ex;
    }
    __syncthreads();
    for (int e = bbase + t; e < bend; e += 256) {
        unsigned int rec = ebuf[e];
        int dl = rec >> 17;
        int s = rec & 0x1FFFF;
        int p = bbase + soff[dl] + atomicAdd(&scur[dl], 1);
        col[p] = s;
    }
    // pre-scaled padded input rows for k_l1 (threads >=128 have exited the loop)
    if (t < 128) {
        int node = b * 128 + t;
        if (node < N_NODES) {
            float4 v0, v1;
            v0.x = dval * x[node * 7 + 0];
            v0.y = dval * x[node * 7 + 1];
            v0.z = dval * x[node * 7 + 2];
            v0.w = dval * x[node * 7 + 3];
            v1.x = dval * x[node * 7 + 4];
            v1.y = dval * x[node * 7 + 5];
            v1.z = dval * x[node * 7 + 6];
            v1.w = 0.f;
            *(float4*)&xs[node * 8] = v0;
            *(float4*)&xs[node * 8 + 4] = v1;
        }
    }
}

// ---------------- fused layer 1: g1 = bf16(dinv * relu((A' x) W1 + b1)) ----------------
// One wave per node. Gather phase: 8 lanes per edge (lane = g*8+r), 8 edges per step,
// acc[r] += xs[s][r]. Self term in GROUP 0 ONLY (butterfly sums across groups).

__global__ __launch_bounds__(256) void k_l1(const float* __restrict__ xs,
                                            const float* __restrict__ W1,
                                            const float* __restrict__ b1,
                                            const int* __restrict__ rowptr,
                                            const int* __restrict__ col,
                                            const float* __restrict__ dinv,
                                            unsigned int* __restrict__ g1) {
    __shared__ float w1s[FIN * HID];   // 3.5 KB
    __shared__ float b1s[HID];
    int t = threadIdx.x;
    for (int i = t; i < FIN * HID; i += 256) w1s[i] = W1[i];
    if (t < HID) b1s[t] = b1[t];
    __syncthreads();

    int lane = t & 63, wave = t >> 6;
    int g = lane >> 3, r = lane & 7;
    int node = blockIdx.x * 4 + wave;            // grid exact: 25000*4 = N_NODES
    float di = dinv[node];
    float acc = (g == 0) ? xs[node * 8 + r] : 0.f;   // self term once (group 0 only)
    int e0 = rowptr[node], e1 = rowptr[node + 1];

    for (int base = e0; base < e1; base += 64) {
        int m = e1 - base; if (m > 64) m = 64;
        int cv = col[base + lane];               // over-read past e1 safe (ebuf region)
        int j = 0;
        for (; j + 8 <= m; j += 8) {
            int s = __shfl(cv, j + g);
            acc += xs[s * 8 + r];
        }
        if (j < m) {
            int jg = j + g;
            int idx = (jg < m) ? jg : j;         // j < m here, so idx always valid
            int s = __shfl(cv, idx);
            float u = xs[s * 8 + r];
            if (jg < m) acc += u;
        }
    }
    // reduce across the 8 edge-groups: every lane gets the full sum for feature r
    acc += __shfl_xor(acc, 8);
    acc += __shfl_xor(acc, 16);
    acc += __shfl_xor(acc, 32);
    acc *= di;                                   // outer dinv_i of the symmetric norm

    // broadcast the 7 aggregated features, project: lane -> outputs 2l, 2l+1
    float av[FIN];
    #pragma unroll
    for (int k = 0; k < FIN; ++k) av[k] = __shfl(acc, k);
    float2 bb = *(const float2*)&b1s[2 * lane];
    float acc0 = bb.x, acc1 = bb.y;
    #pragma unroll
    for (int k = 0; k < FIN; ++k) {
        float2 w = *(const float2*)&w1s[k * HID + 2 * lane];
        acc0 += av[k] * w.x;
        acc1 += av[k] * w.y;
    }
    g1[(size_t)node * 64 + lane] = pack_bf2(di * fmaxf(acc0, 0.f), di * fmaxf(acc1, 0.f));
}

// ---------------- aggregation: wave/node, pre-scaled rows, prefetched windows --------
// At the compulsory-fetch floor (8 XCDs x 25.6 MB buffer ~= 192 MB measured): leave as is.

__global__ __launch_bounds__(256) void k_aggW(const unsigned int* __restrict__ gIn,
                                              unsigned int* __restrict__ gOut,
                                              const int* __restrict__ rowptr,
                                              const int* __restrict__ colv,
                                              const float* __restrict__ dinv) {
    int wid = (blockIdx.x * blockDim.x + threadIdx.x) >> 6;
    int lane = threadIdx.x & 63;
    if (wid >= N_NODES) return;
    int i = wid;
    float di = dinv[i];
    int e0 = rowptr[i], e1 = rowptr[i + 1];
    int cv = colv[e0 + lane];                     // over-read past e1 is safe/unused
    unsigned int v = gIn[(size_t)i * 64 + lane];  // self term (pre-scaled)
    float ax = bf_lo(v), ay = bf_hi(v);

    for (int base = e0; base < e1; base += 64) {
        int m = e1 - base; if (m > 64) m = 64;
        int cvn = cv;
        if (base + 64 < e1) cvn = colv[base + 64 + lane];   // prefetch next window
        int j = 0;
        for (; j + 7 < m; j += 8) {
            int s0 = __shfl(cv, j),     s1 = __shfl(cv, j + 1);
            int s2 = __shfl(cv, j + 2), s3 = __shfl(cv, j + 3);
            int s4 = __shfl(cv, j + 4), s5 = __shfl(cv, j + 5);
            int s6 = __shfl(cv, j + 6), s7 = __shfl(cv, j + 7);
            unsigned int u0 = gIn[(size_t)s0 * 64 + lane];
            unsigned int u1 = gIn[(size_t)s1 * 64 + lane];
            unsigned int u2 = gIn[(size_t)s2 * 64 + lane];
            unsigned int u3 = gIn[(size_t)s3 * 64 + lane];
            unsigned int u4 = gIn[(size_t)s4 * 64 + lane];
            unsigned int u5 = gIn[(size_t)s5 * 64 + lane];
            unsigned int u6 = gIn[(size_t)s6 * 64 + lane];
            unsigned int u7 = gIn[(size_t)s7 * 64 + lane];
            ax += bf_lo(u0); ay += bf_hi(u0);
            ax += bf_lo(u1); ay += bf_hi(u1);
            ax += bf_lo(u2); ay += bf_hi(u2);
            ax += bf_lo(u3); ay += bf_hi(u3);
            ax += bf_lo(u4); ay += bf_hi(u4);
            ax += bf_lo(u5); ay += bf_hi(u5);
            ax += bf_lo(u6); ay += bf_hi(u6);
            ax += bf_lo(u7); ay += bf_hi(u7);
        }
        for (; j + 3 < m; j += 4) {
            int s0 = __shfl(cv, j),     s1 = __shfl(cv, j + 1);
            int s2 = __shfl(cv, j + 2), s3 = __shfl(cv, j + 3);
            unsigned int u0 = gIn[(size_t)s0 * 64 + lane];
            unsigned int u1 = gIn[(size_t)s1 * 64 + lane];
            unsigned int u2 = gIn[(size_t)s2 * 64 + lane];
            unsigned int u3 = gIn[(size_t)s3 * 64 + lane];
            ax += bf_lo(u0); ay += bf_hi(u0);
            ax += bf_lo(u1); ay += bf_hi(u1);
            ax += bf_lo(u2); ay += bf_hi(u2);
            ax += bf_lo(u3); ay += bf_hi(u3);
        }
        for (; j < m; ++j) {
            int s0 = __shfl(cv, j);
            unsigned int u0 = gIn[(size_t)s0 * 64 + lane];
            ax += bf_lo(u0); ay += bf_hi(u0);
        }
        cv = cvn;
    }
    gOut[(size_t)i * 64 + lane] = pack_bf2(di * ax, di * ay);
}

// ---------------- MFMA matmul (layers 2,3): g_out = bf16(dinv * relu(A @ WT^T + b)) ---
// When Wcp != nullptr (layer 3): additionally compute ps[n] = row_n @ Wc and SKIP the
// outg store entirely (g3 is dead once ps exists -> saves a 25.6 MB write + the whole
// k_proj pass). Wc staged into sbuf spare tail [128*132,128*136) — free after the WT
// operand is consumed by the MFMAs and disjoint from the Cs region (stride 132).

__global__ __launch_bounds__(256) void k_mmx(const unsigned int* __restrict__ gIn,
                                             const unsigned short* __restrict__ WTg,
                                             const float* __restrict__ bias,
                                             const float* __restrict__ dinv,
                                             unsigned int* __restrict__ outg,
                                             const float* __restrict__ Wcp,
                                             float2* __restrict__ ps) {
    __shared__ unsigned short sbuf[128 * 136];   // WT (stride 136), reused as Cs (stride 132)
    int t = threadIdx.x;
    // coalesced copy: 16384 shorts, 8 per thread per iter (uint4)
    for (int i = t * 8; i < 128 * 128; i += 256 * 8) {
        int n = i >> 7, k = i & 127;
        uint4 val = *(const uint4*)(WTg + i);
        *(uint4*)(sbuf + n * 136 + k) = val;
    }

    int lane = t & 63, wave = t >> 6;
    int m = lane & 15, quad = lane >> 4;
    int nodeBase = blockIdx.x * 128 + wave * 32;
    const short* gs = (const short*)gIn;

    float bi[8];
    #pragma unroll
    for (int nt = 0; nt < 8; ++nt) bi[nt] = bias[nt * 16 + m];

    f32x4 acc[2][8];
    #pragma unroll
    for (int gi = 0; gi < 2; ++gi)
        #pragma unroll
        for (int nt = 0; nt < 8; ++nt)
            acc[gi][nt] = (f32x4){0.f, 0.f, 0.f, 0.f};

    __syncthreads();

    #pragma unroll
    for (int kc = 0; kc < 4; ++kc) {
        bf16x8 ah[2];
        #pragma unroll
        for (int gi = 0; gi < 2; ++gi) {
            int node = nodeBase + gi * 16 + m;
            bf16x8 h = {0, 0, 0, 0, 0, 0, 0, 0};
            if (node < N_NODES)
                h = *(const bf16x8*)(gs + (size_t)node * 128 + kc * 32 + quad * 8);
            ah[gi] = h;
        }
        #pragma unroll
        for (int nt = 0; nt < 8; ++nt) {
            bf16x8 b = *(const bf16x8*)(sbuf + (nt * 16 + m) * 136 + kc * 32 + quad * 8);
            #pragma unroll
            for (int gi = 0; gi < 2; ++gi)
                acc[gi][nt] = __builtin_amdgcn_mfma_f32_16x16x32_bf16(ah[gi], b, acc[gi][nt], 0, 0, 0);
        }
    }

    __syncthreads();
    float* wcs = (float*)(sbuf + 128 * 132);     // 1 KB spare tail: staged Wc (256 floats)
    if (Wcp != nullptr) wcs[t] = Wcp[t];
    #pragma unroll
    for (int gi = 0; gi < 2; ++gi)
        #pragma unroll
        for (int r = 0; r < 4; ++r) {
            int nl = wave * 32 + gi * 16 + quad * 4 + r;
            int node = blockIdx.x * 128 + nl;
            float di = (node < N_NODES) ? dinv[node] : 0.f;
            #pragma unroll
            for (int nt = 0; nt < 8; ++nt) {
                float vv = acc[gi][nt][r] + bi[nt];
                sbuf[nl * 132 + nt * 16 + m] = (unsigned short)f2bf_rne(di * fmaxf(vv, 0.f));
            }
        }
    __syncthreads();
    if (Wcp == nullptr) {
        for (int i = t; i < 128 * 32; i += 256) {
            int nl = i >> 5, p = i & 31;
            int node = blockIdx.x * 128 + nl;
            if (node < N_NODES) {
                uint2 val = *(const uint2*)(sbuf + nl * 132 + p * 4);
                *(uint2*)&outg[(size_t)node * 64 + p * 2] = val;
            }
        }
    } else {
        // ps[n] = row_n @ Wc : 2 threads per node, 32 packed pairs each, pair-combine
        int nl = t >> 1, half = t & 1;
        int node = blockIdx.x * 128 + nl;
        const unsigned int* row = (const unsigned int*)(sbuf + nl * 132 + half * 64);
        float p0 = 0.f, p1 = 0.f;
        #pragma unroll
        for (int q = 0; q < 32; ++q) {
            unsigned int u = row[q];
            float4 w = *(const float4*)&wcs[(half * 64 + 2 * q) * 2];
            p0 += bf_lo(u) * w.x + bf_hi(u) * w.z;
            p1 += bf_lo(u) * w.y + bf_hi(u) * w.w;
        }
        p0 += __shfl_xor(p0, 1);
        p1 += __shfl_xor(p1, 1);
        if (half == 0 && node < N_NODES) { float2 o; o.x = p0; o.y = p1; ps[node] = o; }
    }
}

// ---------------- tail: per-graph block — aggregate 2-dim vectors + pool + bias ------
// No atomics (R6 lesson: sorted batch + tiny atomic target = same-address RMW serial).
// 16-lane groups own nodes; per-group register accumulation; wave+LDS reduce.

__global__ __launch_bounds__(256) void k_tail(const float2* __restrict__ ps,
                                              const int* __restrict__ rowptr,
                                              const int* __restrict__ col,
                                              const float* __restrict__ dinv,
                                              const int* __restrict__ batch,
                                              const float* __restrict__ bc,
                                              const float* __restrict__ blin,
                                              float* __restrict__ out) {
    __shared__ float red[8];
    int g = blockIdx.x, t = threadIdx.x;
    int lo = 0, hi = N_NODES;
    while (lo < hi) { int mid = (lo + hi) >> 1; if (batch[mid] < g) lo = mid + 1; else hi = mid; }
    int start = lo;
    hi = N_NODES;
    while (lo < hi) { int mid = (lo + hi) >> 1; if (batch[mid] < g + 1) lo = mid + 1; else hi = mid; }
    int end = lo, cnt = end - start;

    int grp = t >> 4, r = t & 15;      // 16 groups of 16 lanes
    float s0 = 0.f, s1 = 0.f;          // only r==0 lanes accumulate node results
    for (int n = start + grp; n < end; n += 16) {
        int e0 = rowptr[n], e1 = rowptr[n + 1];
        float a0 = 0.f, a1 = 0.f;
        for (int e = e0 + r; e < e1; e += 16) {
            float2 pv = ps[col[e]];
            a0 += pv.x; a1 += pv.y;
        }
        #pragma unroll
        for (int sh = 1; sh < 16; sh <<= 1) {
            a0 += __shfl_xor(a0, sh);
            a1 += __shfl_xor(a1, sh);
        }
        if (r == 0) {
            float2 pn = ps[n];
            float di = dinv[n];
            s0 += di * (a0 + pn.x);
            s1 += di * (a1 + pn.y);
        }
    }
    // lanes 0,16,32,48 of each wave hold partials (others are 0)
    s0 += __shfl_xor(s0, 16); s1 += __shfl_xor(s1, 16);
    s0 += __shfl_xor(s0, 32); s1 += __shfl_xor(s1, 32);
    int lane = t & 63, wave = t >> 6;
    if (lane == 0) { red[wave * 2] = s0; red[wave * 2 + 1] = s1; }
    __syncthreads();
    if (t == 0) {
        float r0 = red[0] + red[2] + red[4] + red[6];
        float r1 = red[1] + red[3] + red[5] + red[7];
        if (cnt > 0) {
            float ic = 1.0f / (float)cnt;
            out[g * 2]     = r0 * ic + bc[0];
            out[g * 2 + 1] = r1 * ic + bc[1];
        } else {
            out[g * 2]     = blin[0];
            out[g * 2 + 1] = blin[1];
        }
    }
}

// ---------------- launcher ----------------

extern "C" void kernel_launch(void* const* d_in, const int* in_sizes, int n_in,
                              void* d_out, int out_size, void* d_ws, size_t ws_size,
                              hipStream_t stream) {
    const float* x    = (const float*)d_in[0];
    const int*   eidx = (const int*)d_in[1];
    const int*   batch= (const int*)d_in[2];
    const float* W1   = (const float*)d_in[3];
    const float* b1   = (const float*)d_in[4];
    const float* W2   = (const float*)d_in[5];
    const float* b2   = (const float*)d_in[6];
    const float* W3   = (const float*)d_in[7];
    const float* b3   = (const float*)d_in[8];
    const float* W4   = (const float*)d_in[9];
    const float* b4   = (const float*)d_in[10];
    const float* Wlin = (const float*)d_in[11];
    const float* blin = (const float*)d_in[12];
    float* out = (float*)d_out;

    // workspace carve-up (256B aligned)
    char* ws = (char*)d_ws;
    size_t off = 0;
    auto carve = [&](size_t bytes) { char* p = ws + off; off = (off + bytes + 255) & ~(size_t)255; return p; };
    int*   rowptr    = (int*)carve((size_t)(N_NODES + 1) * 4);
    float* dinv      = (float*)carve((size_t)N_NODES * 4);
    int*   col       = (int*)carve((size_t)E_EDGES * 4);    // k_aggW/k_l1 over-read <=63 ints into ebuf: safe
    unsigned int* ebuf = (unsigned int*)carve((size_t)E_EDGES * 4);
    int*   table     = (int*)carve((size_t)TLEN * 4);
    int*   partial   = (int*)carve((size_t)NCH * 4);
    int*   bucketBase= (int*)carve((size_t)(NBUCK + 1) * 4);
    float* xs        = (float*)carve((size_t)N_NODES * 8 * 4);   // 3.2 MB pre-scaled x (pad 8)
    unsigned int* gA = (unsigned int*)carve((size_t)N_NODES * 64 * 4);   // 25.6 MB bf16 buffer
    unsigned int* gB = (unsigned int*)carve((size_t)N_NODES * 64 * 4);   // 25.6 MB bf16 buffer
    float2* ps       = (float2*)carve((size_t)N_NODES * 8);      // 800 KB projected 2-dim
    float* Wc        = (float*)carve((size_t)HID * 2 * 4);
    float* bc        = (float*)carve(2 * 4);
    unsigned short* WT2 = (unsigned short*)carve((size_t)HID * HID * 2);
    unsigned short* WT3 = (unsigned short*)carve((size_t)HID * HID * 2);
    (void)ws_size; (void)n_in; (void)in_sizes; (void)out_size;

    const int BLK = 256;

    // CSR hist + Wc fold + WT2/WT3 conversion (single fused dispatch)
    k_hist2<<<NBLK_SC + 129, BLK, 0, stream>>>(eidx, table, W4, b4, Wlin, blin,
                                               Wc, bc, W2, W3, WT2, WT3);
    k_blocksum<<<NCH, BLK, 0, stream>>>(table, partial);
    k_scan_final<<<NCH, 1024, 0, stream>>>(table, partial, bucketBase, rowptr);
    k_scatter2<<<NBLK_SC, BLK, 0, stream>>>(eidx, table, ebuf);
    k_bucket<<<NBUCK, BLK, 0, stream>>>(ebuf, bucketBase, rowptr, dinv, col, x, xs);

    // layer 1 (fused agg + matmul), output pre-scaled by dinv
    k_l1<<<L1_GRID, BLK, 0, stream>>>(xs, W1, b1, rowptr, col, dinv, gA);

    // layer 2: a2 = A' g1 -> MFMA mm (pre-scaled out) -> g2
    k_aggW<<<AGGW_GRID, BLK, 0, stream>>>(gA, gB, rowptr, col, dinv);
    k_mmx<<<MMX_GRID, BLK, 0, stream>>>(gB, WT2, b2, dinv, gA, nullptr, nullptr);
    // layer 3: a3 = A' g2 -> MFMA mm fused with layer-4 Wc projection -> ps (g3 dead)
    k_aggW<<<AGGW_GRID, BLK, 0, stream>>>(gA, gB, rowptr, col, dinv);
    k_mmx<<<MMX_GRID, BLK, 0, stream>>>(gB, WT3, b3, dinv, gA, Wc, ps);

    // layer 4: aggregate 2-dim vectors + pool + bias, one block per graph, no atomics
    k_tail<<<NG, BLK, 0, stream>>>(ps, rowptr, col, dinv, batch, bc, blin, out);
}